// Round 11
// baseline (118.758 us; speedup 1.0000x reference)
//
#include <hip/hip_runtime.h>

#define NB 8
#define LEN 256
#define DIM 768
#define NC 3976
// output layout (floats): fofe_codes [8][3976][5][768] = 122142720,
// cands_pos [8][3976][2] = 63616, padded [8][3976] = 31808
#define OFF_POS 122142720
#define OFF_PAD (122142720 + 63616)
#define NROWS (NB * NC * 5)  // 159040 fofe rows of 768 floats
#define NBLK 2048

constexpr float ALPHA_F = 0.9f;
constexpr float A32 = 0.03433683820292512f;  // 0.9^32

typedef float f4 __attribute__((ext_vector_type(4)));

__device__ __constant__ float APOW[17] = {
    1.f, 0.9f, 0.81f, 0.729f, 0.6561f, 0.59049f, 0.531441f, 0.4782969f,
    0.43046721f, 0.387420489f, 0.3486784401f, 0.31381059609f, 0.282429536481f,
    0.2541865828329f, 0.22876792454961f, 0.205891132094649f, 0.1853020188851841f};

// Prefix/suffix geometric scan: P[l] = x[l] + a*P[l-1], S[l] = x[l] + a*S[l+1].
// block = 256 threads: 32 d-lanes x 8 l-chunks (32 elems each).
// grid = (DIM/32 = 24, NB, 2 directions)
__global__ __launch_bounds__(256) void scan_kernel(const float* __restrict__ x,
                                                   float* __restrict__ P,
                                                   float* __restrict__ S) {
    const int dl = threadIdx.x & 31;
    const int chunk = threadIdx.x >> 5;
    const int d = blockIdx.x * 32 + dl;
    const int b = blockIdx.y;
    const int dir = blockIdx.z;
    const float* __restrict__ xb = x + (size_t)b * LEN * DIM;
    float* __restrict__ ob = (dir ? S : P) + (size_t)b * LEN * DIM;

    float vals[32];
    float acc = 0.f;
#pragma unroll
    for (int t = 0; t < 32; ++t) {
        const int lm = chunk * 32 + t;
        const int l = dir ? (LEN - 1 - lm) : lm;
        acc = fmaf(ALPHA_F, acc, xb[l * DIM + d]);
        vals[t] = acc;
    }

    __shared__ float ends[8][32];
    ends[chunk][dl] = acc;
    __syncthreads();

    // carry into this chunk: C_k = end[k-1] + a^32 * C_{k-1}
    float carry = 0.f;
    for (int k = 0; k < chunk; ++k)
        carry = fmaf(A32, carry, ends[k][dl]);

    float w = ALPHA_F;
#pragma unroll
    for (int t = 0; t < 32; ++t) {
        const int lm = chunk * 32 + t;
        const int l = dir ? (LEN - 1 - lm) : lm;
        ob[l * DIM + d] = fmaf(w, carry, vals[t]);
        w *= ALPHA_F;
    }
}

// R7 grid-stride ROW SWEEP, but BRANCH-FREE gather: every row is uniformly
// v = scale1*ld(src1) - coef*ld(src2) with clamped always-valid addresses, so
// the compiler can software-pipeline loads across iterations (unroll 2 gives
// two independent load->store chains). Write pattern identical to R7.
__global__ __launch_bounds__(192) void row_kernel(const float* __restrict__ P,
                                                  const float* __restrict__ S,
                                                  const int* __restrict__ mask,
                                                  float* __restrict__ out) {
    const int t = threadIdx.x;
    const f4* __restrict__ P4 = (const f4*)P;
    const f4* __restrict__ S4 = (const f4*)S;
    f4* __restrict__ out4 = (f4*)out;

#pragma unroll 2
    for (int row = blockIdx.x; row < NROWS; row += NBLK) {
        const int bc = row / 5;
        const int which = row - bc * 5;
        const int b = bc / NC;
        const int c = bc - b * NC;
        // decode candidate c -> (start i, span s)
        int i, s;
        if (c < 3856) {
            i = c >> 4;
            s = c & 15;
        } else {
            const int r = c - 3856;
            int u = 0, off = 0;
            while (off + (15 - u) <= r) { off += 15 - u; ++u; }
            i = 241 + u;
            s = r - off;
        }
        const int e = i + s;
        // branch-free source decode:
        //   which 0: P[i-1] (zero if i==0)      1: P[e]      2: P[e]-a^(s+1)P[i-1]
        //   which 3: S[i]                       4: S[e+1] (zero if e==LEN-1)
        const int r1 = (which == 0) ? (i - 1) : (which <= 2) ? e : (which == 3) ? i : (e + 1);
        const int r1c = min(max(r1, 0), LEN - 1);
        const float scale1 =
            ((which == 0 && i == 0) || (which == 4 && e == LEN - 1)) ? 0.f : 1.f;
        const float coef = (which == 2 && i > 0) ? APOW[s + 1] : 0.f;
        const f4* __restrict__ src1 = ((which < 3) ? P4 : S4) + (size_t)(b * LEN + r1c) * 192;
        const f4* __restrict__ src2 = P4 + (size_t)(b * LEN + max(i - 1, 0)) * 192;

        const f4 ld1 = src1[t];
        const f4 ld2 = src2[t];
        out4[(size_t)row * 192 + t] = scale1 * ld1 - coef * ld2;
    }

    // tail: cands_pos + padded_cands, one (b, start i) per block
    {
        const int r2 = blockIdx.x;
        const int b = r2 >> 8;
        const int i = r2 & 255;
        int n, c0;
        if (i <= 240) {
            n = 16;
            c0 = i * 16;
        } else {
            const int r = LEN - i;  // 15..1
            n = r;
            c0 = 3856 + 120 - r * (r + 1) / 2;
        }
        if (t < 64) {  // wave 0 only
            const int m = (t < n) ? mask[b * LEN + i + t] : 0;
            const unsigned long long ball = __ballot(m != 0);
            if (t < n) {
                const size_t c = (size_t)(b * NC + c0 + t);
                out[OFF_POS + c * 2] = (float)i;
                out[OFF_POS + c * 2 + 1] = (float)(i + t);
                // window [i, i+t]: any mask bit among ballot bits 0..t
                out[OFF_PAD + c] = (ball & ((2ull << t) - 1)) ? 1.f : 0.f;
            }
        }
    }
}

extern "C" void kernel_launch(void* const* d_in, const int* in_sizes, int n_in,
                              void* d_out, int out_size, void* d_ws, size_t ws_size,
                              hipStream_t stream) {
    const float* x = (const float*)d_in[0];
    const int* mask = (const int*)d_in[1];
    float* out = (float*)d_out;
    float* P = (float*)d_ws;                  // [8][256][768] fp32
    float* S = P + (size_t)NB * LEN * DIM;    // [8][256][768] fp32  (12.6 MB total)

    scan_kernel<<<dim3(DIM / 32, NB, 2), 256, 0, stream>>>(x, P, S);
    row_kernel<<<NBLK, 192, 0, stream>>>(P, S, mask, out);
}

// Round 12
// 104.309 us; speedup vs baseline: 1.1385x; 1.1385x over previous
//
#include <hip/hip_runtime.h>

#define NB 8
#define LEN 256
#define DIM 768
#define NC 3976
// output layout (floats): fofe_codes [8][3976][5][768] = 122142720,
// cands_pos [8][3976][2] = 63616, padded [8][3976] = 31808
#define OFF_POS 122142720
#define OFF_PAD (122142720 + 63616)
#define NROWS (NB * NC * 5)        // 159040 fofe rows of 768 floats
#define NVROWS (NROWS + NB * LEN)  // + 2048 virtual rows for pos/pad
#define NBLK 2048

constexpr float ALPHA_F = 0.9f;
constexpr float A32 = 0.03433683820292512f;  // 0.9^32

typedef float f4 __attribute__((ext_vector_type(4)));

__device__ __constant__ float APOW[17] = {
    1.f, 0.9f, 0.81f, 0.729f, 0.6561f, 0.59049f, 0.531441f, 0.4782969f,
    0.43046721f, 0.387420489f, 0.3486784401f, 0.31381059609f, 0.282429536481f,
    0.2541865828329f, 0.22876792454961f, 0.205891132094649f, 0.1853020188851841f};

// Prefix/suffix geometric scan: P[l] = x[l] + a*P[l-1], S[l] = x[l] + a*S[l+1].
// block = 256 threads: 32 d-lanes x 8 l-chunks (32 elems each).
// grid = (DIM/32 = 24, NB, 2 directions)
__global__ __launch_bounds__(256) void scan_kernel(const float* __restrict__ x,
                                                   float* __restrict__ P,
                                                   float* __restrict__ S) {
    const int dl = threadIdx.x & 31;
    const int chunk = threadIdx.x >> 5;
    const int d = blockIdx.x * 32 + dl;
    const int b = blockIdx.y;
    const int dir = blockIdx.z;
    const float* __restrict__ xb = x + (size_t)b * LEN * DIM;
    float* __restrict__ ob = (dir ? S : P) + (size_t)b * LEN * DIM;

    float vals[32];
    float acc = 0.f;
#pragma unroll
    for (int t = 0; t < 32; ++t) {
        const int lm = chunk * 32 + t;
        const int l = dir ? (LEN - 1 - lm) : lm;
        acc = fmaf(ALPHA_F, acc, xb[l * DIM + d]);
        vals[t] = acc;
    }

    __shared__ float ends[8][32];
    ends[chunk][dl] = acc;
    __syncthreads();

    // carry into this chunk: C_k = end[k-1] + a^32 * C_{k-1}
    float carry = 0.f;
    for (int k = 0; k < chunk; ++k)
        carry = fmaf(A32, carry, ends[k][dl]);

    float w = ALPHA_F;
#pragma unroll
    for (int t = 0; t < 32; ++t) {
        const int lm = chunk * 32 + t;
        const int l = dir ? (LEN - 1 - lm) : lm;
        ob[l * DIM + d] = fmaf(w, carry, vals[t]);
        w *= ALPHA_F;
    }
}

// Grid-stride ROW SWEEP (fill-kernel-mimicking write pattern): at step q all
// NBLK blocks write rows q*NBLK..q*NBLK+NBLK-1 — a contiguous ~6 MB window
// advancing linearly through the 489 MB output (DRAM row locality like the
// 6.9 TB/s fillBuffer). One 3072 B row per block per step (192 lanes x 16 B).
// Sources are 1-2 P/S rows (12.6 MB total, L3-resident), decode wave-uniform.
__global__ __launch_bounds__(192) void row_kernel(const float* __restrict__ P,
                                                  const float* __restrict__ S,
                                                  const int* __restrict__ mask,
                                                  float* __restrict__ out) {
    const int t = threadIdx.x;
    const f4* __restrict__ P4 = (const f4*)P;
    const f4* __restrict__ S4 = (const f4*)S;
    f4* __restrict__ out4 = (f4*)out;

    for (int row = blockIdx.x; row < NVROWS; row += NBLK) {
        if (row < NROWS) {
            const int bc = row / 5;
            const int which = row - bc * 5;
            const int b = bc / NC;
            const int c = bc - b * NC;
            // decode candidate c -> (start i, span s)
            int i, s;
            if (c < 3856) {
                i = c >> 4;
                s = c & 15;
            } else {
                const int r = c - 3856;
                int u = 0, off = 0;
                while (off + (15 - u) <= r) { off += 15 - u; ++u; }
                i = 241 + u;
                s = r - off;
            }
            const int e = i + s;
            const int base = b * LEN;
            f4 v;
            if (which == 0) {  // left excl: P[i-1]
                v = (i > 0) ? P4[(size_t)(base + i - 1) * 192 + t] : (f4)0.f;
            } else if (which == 1) {  // left incl: P[e]
                v = P4[(size_t)(base + e) * 192 + t];
            } else if (which == 2) {  // cand: P[e] - a^(s+1)*P[i-1]
                const f4 pe = P4[(size_t)(base + e) * 192 + t];
                v = pe;
                if (i > 0) v = pe - APOW[s + 1] * P4[(size_t)(base + i - 1) * 192 + t];
            } else if (which == 3) {  // right incl: S[i]
                v = S4[(size_t)(base + i) * 192 + t];
            } else {  // right excl: S[e+1]
                v = (e < LEN - 1) ? S4[(size_t)(base + e + 1) * 192 + t] : (f4)0.f;
            }
            out4[(size_t)row * 192 + t] = v;
        } else {
            // virtual rows: cands_pos + padded_cands for one (b, start i)
            const int r2 = row - NROWS;
            const int b = r2 >> 8;
            const int i = r2 & 255;
            int n, c0;
            if (i <= 240) {
                n = 16;
                c0 = i * 16;
            } else {
                const int r = LEN - i;  // 15..1
                n = r;
                c0 = 3856 + 120 - r * (r + 1) / 2;
            }
            if (t < 64) {  // wave 0 only
                const int m = (t < n) ? mask[b * LEN + i + t] : 0;
                const unsigned long long ball = __ballot(m != 0);
                if (t < n) {
                    const size_t c = (size_t)(b * NC + c0 + t);
                    out[OFF_POS + c * 2] = (float)i;
                    out[OFF_POS + c * 2 + 1] = (float)(i + t);
                    // window [i, i+t]: any mask bit among ballot bits 0..t
                    out[OFF_PAD + c] = (ball & ((2ull << t) - 1)) ? 1.f : 0.f;
                }
            }
        }
    }
}

extern "C" void kernel_launch(void* const* d_in, const int* in_sizes, int n_in,
                              void* d_out, int out_size, void* d_ws, size_t ws_size,
                              hipStream_t stream) {
    const float* x = (const float*)d_in[0];
    const int* mask = (const int*)d_in[1];
    float* out = (float*)d_out;
    float* P = (float*)d_ws;                  // [8][256][768] fp32
    float* S = P + (size_t)NB * LEN * DIM;    // [8][256][768] fp32  (12.6 MB total)

    scan_kernel<<<dim3(DIM / 32, NB, 2), 256, 0, stream>>>(x, P, S);
    row_kernel<<<NBLK, 192, 0, stream>>>(P, S, mask, out);
}